// Round 2
// baseline (1928.599 us; speedup 1.0000x reference)
//
#include <hip/hip_runtime.h>
#include <hip/hip_bf16.h>
#include <hip/hip_fp16.h>
#include <math.h>

#define NFEAT 512
#define H1 300
#define H2 200
#define NCLASS 40

typedef __attribute__((ext_vector_type(8))) _Float16 half8;
typedef __attribute__((ext_vector_type(4))) float f32x4;
typedef __attribute__((ext_vector_type(2))) unsigned int u32x2;

__device__ __forceinline__ void stage16(const void* gptr, void* ldsptr) {
    __builtin_amdgcn_global_load_lds(
        (const __attribute__((address_space(1))) unsigned int*)gptr,
        (__attribute__((address_space(3))) unsigned int*)ldsptr,
        16, 0, 0);
}

__device__ __forceinline__ unsigned short f2h(float f) {
    return __half_as_ushort(__float2half(f));
}
__device__ __forceinline__ float h2f(unsigned short u) {
    return __half2float(__ushort_as_half(u));
}
__device__ __forceinline__ float2 h2f2(unsigned int u) {
    __half2 h = *reinterpret_cast<__half2*>(&u);
    return __half22float2(h);
}
__device__ __forceinline__ unsigned pack2h(float a, float b) {
    return (unsigned)f2h(a) | ((unsigned)f2h(b) << 16);
}

// ---------------- CSR construction ----------------

__global__ __launch_bounds__(256) void count_dst_kernel(const int* __restrict__ dst,
                                                        int* __restrict__ counts, int E) {
    int i = blockIdx.x * blockDim.x + threadIdx.x;
    if (i < E) atomicAdd(&counts[dst[i]], 1);
}

__global__ __launch_bounds__(1024) void scan_kernel(const int* __restrict__ counts,
                                                    int* __restrict__ row_ptr,
                                                    int* __restrict__ nextp, int N) {
    __shared__ int sums[1024];
    const int tid = threadIdx.x;
    const int CH = (N + 1023) >> 10;
    const int b = tid * CH;
    const int e = min(b + CH, N);
    int s = 0;
    for (int i = b; i < e; i++) s += counts[i];
    sums[tid] = s;
    __syncthreads();
    #pragma unroll
    for (int off = 1; off < 1024; off <<= 1) {
        int t = (tid >= off) ? sums[tid - off] : 0;
        __syncthreads();
        sums[tid] += t;
        __syncthreads();
    }
    int run = (tid > 0) ? sums[tid - 1] : 0;
    for (int i = b; i < e; i++) {
        row_ptr[i] = run;
        nextp[i] = run;
        run += counts[i];
    }
    if (tid == 0) row_ptr[N] = sums[1023];
}

__global__ __launch_bounds__(256) void fill_csr_kernel(const int* __restrict__ src,
                                                       const int* __restrict__ dst,
                                                       const float* __restrict__ ew,
                                                       int* __restrict__ next,
                                                       int2* __restrict__ csr_sw, int E) {
    int i = blockIdx.x * blockDim.x + threadIdx.x;
    if (i < E) {
        int d = dst[i];
        int pos = atomicAdd(&next[d], 1);
        csr_sw[pos] = make_int2(src[i], __float_as_int(ew[i]));
    }
}

// ---------------- X -> fp16 one-shot conversion ----------------

__global__ __launch_bounds__(256) void convert_x_kernel(const float* __restrict__ x,
                                                        unsigned short* __restrict__ X16,
                                                        int total8) {
    int stride = gridDim.x * 256;
    for (int i = blockIdx.x * 256 + threadIdx.x; i < total8; i += stride) {
        const float* p = x + (size_t)i * 8;
        float4 a = *(const float4*)p;
        float4 b = *(const float4*)(p + 4);
        half8 h;
        h[0] = (_Float16)a.x; h[1] = (_Float16)a.y;
        h[2] = (_Float16)a.z; h[3] = (_Float16)a.w;
        h[4] = (_Float16)b.x; h[5] = (_Float16)b.y;
        h[6] = (_Float16)b.z; h[7] = (_Float16)b.w;
        *(half8*)(X16 + (size_t)i * 8) = h;
    }
}

// ---------------- fused weight split: w [K][N] fp32 -> [NPAD][KPAD] fp16 hi/lo ----------------

__global__ __launch_bounds__(256) void split_weights_kernel(
        const float* __restrict__ w1, const float* __restrict__ w2, const float* __restrict__ w3,
        unsigned short* __restrict__ W1H, unsigned short* __restrict__ W1L,
        unsigned short* __restrict__ W2H, unsigned short* __restrict__ W2L,
        unsigned short* __restrict__ W3H, unsigned short* __restrict__ W3L) {
    int i = blockIdx.x * 256 + threadIdx.x;
    const float* w; unsigned short *H, *L; int K, N, KP;
    if (i < 163840) {                       // 320*512
        w = w1; H = W1H; L = W1L; K = 512; N = 300; KP = 512;
    } else if (i < 163840 + 81920) {        // 256*320
        i -= 163840; w = w2; H = W2H; L = W2L; K = 300; N = 200; KP = 320;
    } else {                                // 64*256
        i -= 245760; w = w3; H = W3H; L = W3L; K = 200; N = 40; KP = 256;
    }
    int n = i / KP, k = i - n * KP;
    float a = (n < N && k < K) ? w[(size_t)k * N + n] : 0.f;
    unsigned short h = f2h(a);
    H[i] = h;
    L[i] = f2h(a - h2f(h));
}

// ---------------- fp16 MFMA GEMM: B-only LDS, A direct global->VGPR ----------------

template <int KPAD, int NT, bool AF32>
__global__ __launch_bounds__(256, 3) void gemm_f16_kernel(
        const void* __restrict__ A_,
        const unsigned short* __restrict__ Bhi, const unsigned short* __restrict__ Blo,
        unsigned short* __restrict__ C, int M, int NP, int MT) {
    __shared__ short Bs_hi[4096];
    __shared__ short Bs_lo[4096];

    const int id = blockIdx.x;
    const int g  = id / (8 * NT);
    const int r  = id % (8 * NT);
    const int nt = r >> 3;
    const int x  = r & 7;
    const int mt = g * 8 + x;
    if (mt >= MT) return;

    const int tid = threadIdx.x;
    const int wave = tid >> 6, lane = tid & 63;
    const int lm = lane & 15, quad = lane >> 4;
    const int bm = mt * 256, bn = nt * 64;

    f32x4 acc[4][4] = {};

    for (int k0 = 0; k0 < KPAD; k0 += 64) {
        #pragma unroll
        for (int i = 0; i < 2; i++) {
            int t = i * 256 + tid;
            int n = t >> 3;
            int c = (t & 7) ^ (n & 7);
            size_t goff = (size_t)(bn + n) * KPAD + (size_t)(k0 + c * 8);
            int lbase = (i * 256 + wave * 64) * 8;
            stage16(Bhi + goff, Bs_hi + lbase);
            stage16(Blo + goff, Bs_lo + lbase);
        }
        __syncthreads();

        #pragma unroll
        for (int h = 0; h < 2; h++) {
            const int cidx = h * 4 + quad;
            half8 a[4], bh[4], bl[4];
            #pragma unroll
            for (int i = 0; i < 4; i++) {
                int row = bm + wave * 64 + i * 16 + lm;
                row = row < M ? row : M - 1;
                size_t off = (size_t)row * KPAD + (size_t)(k0 + cidx * 8);
                if (AF32) {
                    const float* ap = (const float*)A_ + off;
                    float4 p = *(const float4*)ap;
                    float4 q = *(const float4*)(ap + 4);
                    half8 t8;
                    t8[0] = (_Float16)p.x; t8[1] = (_Float16)p.y;
                    t8[2] = (_Float16)p.z; t8[3] = (_Float16)p.w;
                    t8[4] = (_Float16)q.x; t8[5] = (_Float16)q.y;
                    t8[6] = (_Float16)q.z; t8[7] = (_Float16)q.w;
                    a[i] = t8;
                } else {
                    a[i] = *(const half8*)((const unsigned short*)A_ + off);
                }
            }
            #pragma unroll
            for (int j = 0; j < 4; j++) {
                int n = j * 16 + lm;
                int off = (n * 8 + (cidx ^ (n & 7))) * 8;
                bh[j] = *(const half8*)(Bs_hi + off);
                bl[j] = *(const half8*)(Bs_lo + off);
            }
            #pragma unroll
            for (int i = 0; i < 4; i++)
                #pragma unroll
                for (int j = 0; j < 4; j++) {
                    acc[i][j] = __builtin_amdgcn_mfma_f32_16x16x32_f16(a[i], bh[j], acc[i][j], 0, 0, 0);
                    acc[i][j] = __builtin_amdgcn_mfma_f32_16x16x32_f16(a[i], bl[j], acc[i][j], 0, 0, 0);
                }
        }
        __syncthreads();
    }

    #pragma unroll
    for (int i = 0; i < 4; i++) {
        #pragma unroll
        for (int j = 0; j < 4; j++) {
            #pragma unroll
            for (int r2 = 0; r2 < 4; r2++) {
                int row = bm + wave * 64 + i * 16 + quad * 4 + r2;
                int col = bn + j * 16 + lm;
                if (row < M)
                    C[(size_t)row * NP + col] = f2h(acc[i][j][r2]);
            }
        }
    }
}

// ---------------- SpMM (CSR by dst), persistent-block, one wave per dst row ----------------
// WIDE (layer1, F=300): one dwordx4 gather per edge, lanes 0..37 cover 304 feats.
// narrow (layer2, F=200): one dwordx2 gather per edge, lanes 0..49 cover 200 feats.
// 8-edge batches, csr segment read lane-parallel (1 load) + readlane broadcast;
// addresses clamped -> branch-free, all 8 gathers held live in VGPRs.

template <int F, int NP>
__global__ __launch_bounds__(256, 8) void spmm_relu_f16_kernel(
        const int* __restrict__ row_ptr, const int2* __restrict__ csr_sw,
        const unsigned short* __restrict__ support, const float* __restrict__ bias,
        unsigned short* __restrict__ outp, int N) {
    constexpr bool WIDE = ((F + 3) / 4 > 64);
    constexpr int LPE = WIDE ? (F + 7) / 8 : (F + 3) / 4;   // lanes per edge
    constexpr int AK  = WIDE ? 8 : 4;                       // feats per lane

    const int lane = threadIdx.x & 63;
    const int nwaves = gridDim.x * 4;
    const int lc = min(lane, LPE - 1);

    for (int row = blockIdx.x * 4 + (threadIdx.x >> 6); row < N; row += nwaves) {
        const int beg = row_ptr[row], end = row_ptr[row + 1];
        float acc[AK];
        #pragma unroll
        for (int k = 0; k < AK; k++) acc[k] = 0.f;

        int e = beg;
        int2 swv;
        if (e < end) swv = csr_sw[e + min(lane, min(end - e, 8) - 1)];
        while (e < end) {
            const int m = min(end - e, 8);
            const int2 cur = swv;
            int s_[8]; float w_[8];
            #pragma unroll
            for (int q = 0; q < 8; q++) {
                int qq = min(q, m - 1);
                s_[q] = __builtin_amdgcn_readlane(cur.x, qq);
                float wv = __uint_as_float((unsigned)__builtin_amdgcn_readlane(cur.y, qq));
                w_[q] = (q < m) ? wv : 0.f;
            }
            half8 u8[8]; u32x2 u4[8];
            #pragma unroll
            for (int q = 0; q < 8; q++) {
                const unsigned short* sp = support + (size_t)s_[q] * NP;
                if (WIDE) u8[q] = *(const half8*)(sp + lc * 8);
                else      u4[q] = *(const u32x2*)(sp + lc * 4);
            }
            const int enext = e + m;
            if (enext < end) swv = csr_sw[enext + min(lane, min(end - enext, 8) - 1)];
            #pragma unroll
            for (int q = 0; q < 8; q++) {
                if (WIDE) {
                    #pragma unroll
                    for (int k = 0; k < 8; k++) acc[k] += w_[q] * (float)u8[q][k];
                } else {
                    float2 a0 = h2f2(u4[q].x), a1 = h2f2(u4[q].y);
                    acc[0] += w_[q] * a0.x;
                    acc[1] += w_[q] * a0.y;
                    acc[2] += w_[q] * a1.x;
                    acc[3] += w_[q] * a1.y;
                }
            }
            e = enext;
        }

        if (WIDE) {
            if (lane * 8 < NP) {
                half8 o;
                #pragma unroll
                for (int k = 0; k < 8; k++) {
                    int f = lane * 8 + k;
                    float v = 0.f;
                    if (f < F && lane < LPE) v = fmaxf(acc[k] + bias[f], 0.f);
                    o[k] = (_Float16)v;
                }
                *(half8*)(outp + (size_t)row * NP + lane * 8) = o;
            }
        } else {
            bool real = lane < LPE;
            float4 bb = real ? ((const float4*)bias)[lane] : make_float4(0, 0, 0, 0);
            float v0 = real ? fmaxf(acc[0] + bb.x, 0.f) : 0.f;
            float v1 = real ? fmaxf(acc[1] + bb.y, 0.f) : 0.f;
            float v2 = real ? fmaxf(acc[2] + bb.z, 0.f) : 0.f;
            float v3 = real ? fmaxf(acc[3] + bb.w, 0.f) : 0.f;
            u32x2 w;
            w.x = pack2h(v0, v1);
            w.y = pack2h(v2, v3);
            *(u32x2*)(outp + (size_t)row * NP + lane * 4) = w;
        }
    }
}

// layer 3: aggregation (F=40, stride 64 fp16) + bias + softmax fused, persistent blocks.

__global__ __launch_bounds__(256) void spmm_softmax_kernel(
        const int* __restrict__ row_ptr, const int2* __restrict__ csr_sw,
        const unsigned short* __restrict__ support, const float* __restrict__ bias,
        float* __restrict__ out, int N) {
    const int lane = threadIdx.x & 63;
    const int nwaves = gridDim.x * 4;

    const int g = lane / 20;           // 0,1,2 active; 3 = idle lanes 60-63
    const int t = lane - g * 20;       // 0..19 (class dword index)
    const bool lact = lane < 60;

    for (int row = blockIdx.x * 4 + (threadIdx.x >> 6); row < N; row += nwaves) {
        int beg = row_ptr[row], end = row_ptr[row + 1];

        float a0 = 0.f, a1 = 0.f;
        for (int e = beg; e < end; e += 3) {
            int ei = e + g;
            bool v = lact && (ei < end);
            int2 sw = csr_sw[v ? ei : beg];
            float w = v ? __int_as_float(sw.y) : 0.f;
            unsigned u = *(const unsigned*)(support + (size_t)sw.x * 64 + t * 2);
            float2 aa = h2f2(u);
            a0 += w * aa.x;
            a1 += w * aa.y;
        }
        a0 += __shfl(a0, lane + 20) + __shfl(a0, lane + 40);
        a1 += __shfl(a1, lane + 20) + __shfl(a1, lane + 40);

        const bool act = lane < 20;
        float v0 = 0.f, v1 = 0.f, m = -INFINITY;
        if (act) {
            float2 bb = ((const float2*)bias)[t];
            v0 = a0 + bb.x;
            v1 = a1 + bb.y;
            m = fmaxf(v0, v1);
        }
        #pragma unroll
        for (int off = 16; off; off >>= 1) m = fmaxf(m, __shfl_xor(m, off));
        float e0 = 0.f, e1 = 0.f;
        if (act) { e0 = expf(v0 - m); e1 = expf(v1 - m); }
        float s = e0 + e1;
        #pragma unroll
        for (int off = 16; off; off >>= 1) s += __shfl_xor(s, off);
        if (act) {
            float inv = 1.f / s;
            *(float2*)(out + (size_t)row * NCLASS + t * 2) = make_float2(e0 * inv, e1 * inv);
        }
    }
}

// ---------------- launch ----------------

extern "C" void kernel_launch(void* const* d_in, const int* in_sizes, int n_in,
                              void* d_out, int out_size, void* d_ws, size_t ws_size,
                              hipStream_t stream) {
    const float* x   = (const float*)d_in[0];
    const int*   ei  = (const int*)d_in[1];
    const float* ew  = (const float*)d_in[2];
    const float* w1  = (const float*)d_in[3];
    const float* b1  = (const float*)d_in[4];
    const float* w2  = (const float*)d_in[5];
    const float* b2  = (const float*)d_in[6];
    const float* w3  = (const float*)d_in[7];
    const float* b3  = (const float*)d_in[8];
    float* out = (float*)d_out;

    const int N = in_sizes[0] / NFEAT;   // 100000
    const int E = in_sizes[2];           // 3200000
    const int* src = ei;
    const int* dst = ei + E;

    const int KP1 = 512, NP1 = 320, NT1 = 5;   // layer1: K=512, N=300
    const int KP2 = 320, NP2 = 256, NT2 = 4;   // layer2: K=300, N=200
    const int KP3 = 256, NP3 = 64,  NT3 = 1;   // layer3: K=200, N=40

    char* base = (char*)d_ws;
    unsigned short* X16 = (unsigned short*)(base);   // 100000*512*2, dead after gemm1
    unsigned short* H1H = (unsigned short*)(base);   // 100000*320*2 overlay
    unsigned short* H2H = (unsigned short*)(base);   // 100000*256*2 overlay

    unsigned short* support = (unsigned short*)(base + 102400256);

    size_t wo = 102400256 + 64000256;
    auto walloc = [&](size_t bytes) { void* r = base + wo; wo += (bytes + 255) & ~(size_t)255; return r; };
    unsigned short* W1H = (unsigned short*)walloc((size_t)NP1 * KP1 * 2);
    unsigned short* W1L = (unsigned short*)walloc((size_t)NP1 * KP1 * 2);
    unsigned short* W2H = (unsigned short*)walloc((size_t)NP2 * KP2 * 2);
    unsigned short* W2L = (unsigned short*)walloc((size_t)NP2 * KP2 * 2);
    unsigned short* W3H = (unsigned short*)walloc((size_t)NP3 * KP3 * 2);
    unsigned short* W3L = (unsigned short*)walloc((size_t)NP3 * KP3 * 2);
    int*  counts  = (int*)walloc((size_t)N * 4);
    int*  row_ptr = (int*)walloc((size_t)(N + 1) * 4);
    int*  nextp   = (int*)walloc((size_t)N * 4);
    int2* csr_sw  = (int2*)walloc((size_t)E * 8);

    const int MT = (N + 255) / 256;              // 391 M-tiles
    const int G  = (MT + 7) / 8;
    const int SPMM_BLOCKS = 2048;                // 8 blocks/CU, persistent

    // ---- CSR build ----
    hipMemsetAsync(counts, 0, (size_t)N * 4, stream);
    count_dst_kernel<<<(E + 255) / 256, 256, 0, stream>>>(dst, counts, E);
    scan_kernel<<<1, 1024, 0, stream>>>(counts, row_ptr, nextp, N);
    fill_csr_kernel<<<(E + 255) / 256, 256, 0, stream>>>(src, dst, ew, nextp, csr_sw, E);

    // ---- weight conversion + X conversion ----
    split_weights_kernel<<<1024, 256, 0, stream>>>(w1, w2, w3, W1H, W1L, W2H, W2L, W3H, W3L);
    convert_x_kernel<<<2048, 256, 0, stream>>>(x, X16, N * NFEAT / 8);

    // ---- layer 1 ----
    gemm_f16_kernel<KP1, NT1, false><<<G * 8 * NT1, 256, 0, stream>>>(
        X16, W1H, W1L, support, N, NP1, MT);
    spmm_relu_f16_kernel<H1, NP1><<<SPMM_BLOCKS, 256, 0, stream>>>(row_ptr, csr_sw, support, b1, H1H, N);

    // ---- layer 2 ----
    gemm_f16_kernel<KP2, NT2, false><<<G * 8 * NT2, 256, 0, stream>>>(
        H1H, W2H, W2L, support, N, NP2, MT);
    spmm_relu_f16_kernel<H2, NP2><<<SPMM_BLOCKS, 256, 0, stream>>>(row_ptr, csr_sw, support, b2, H2H, N);

    // ---- layer 3 ----
    gemm_f16_kernel<KP3, NT3, false><<<G * 8 * NT3, 256, 0, stream>>>(
        H2H, W3H, W3L, support, N, NP3, MT);
    spmm_softmax_kernel<<<SPMM_BLOCKS, 256, 0, stream>>>(row_ptr, csr_sw, support, b3, out, N);
}

// Round 4
// 1724.810 us; speedup vs baseline: 1.1182x; 1.1182x over previous
//
#include <hip/hip_runtime.h>
#include <hip/hip_bf16.h>
#include <hip/hip_fp16.h>
#include <math.h>

#define NFEAT 512
#define H1 300
#define H2 200
#define NCLASS 40

typedef __attribute__((ext_vector_type(8))) _Float16 half8;
typedef __attribute__((ext_vector_type(4))) float f32x4;
typedef __attribute__((ext_vector_type(2))) unsigned int u32x2;

__device__ __forceinline__ void stage16(const void* gptr, void* ldsptr) {
    __builtin_amdgcn_global_load_lds(
        (const __attribute__((address_space(1))) unsigned int*)gptr,
        (__attribute__((address_space(3))) unsigned int*)ldsptr,
        16, 0, 0);
}

__device__ __forceinline__ unsigned short f2h(float f) {
    return __half_as_ushort(__float2half(f));
}
__device__ __forceinline__ float h2f(unsigned short u) {
    return __half2float(__ushort_as_half(u));
}
__device__ __forceinline__ float2 h2f2(unsigned int u) {
    __half2 h = *reinterpret_cast<__half2*>(&u);
    return __half22float2(h);
}
__device__ __forceinline__ unsigned pack2h(float a, float b) {
    return (unsigned)f2h(a) | ((unsigned)f2h(b) << 16);
}

// ---------------- CSR construction ----------------

__global__ __launch_bounds__(256) void count_dst_kernel(const int* __restrict__ dst,
                                                        int* __restrict__ counts, int E) {
    int i = blockIdx.x * blockDim.x + threadIdx.x;
    if (i < E) atomicAdd(&counts[dst[i]], 1);
}

__global__ __launch_bounds__(1024) void scan_kernel(const int* __restrict__ counts,
                                                    int* __restrict__ row_ptr,
                                                    int* __restrict__ nextp, int N) {
    __shared__ int sums[1024];
    const int tid = threadIdx.x;
    const int CH = (N + 1023) >> 10;
    const int b = tid * CH;
    const int e = min(b + CH, N);
    int s = 0;
    for (int i = b; i < e; i++) s += counts[i];
    sums[tid] = s;
    __syncthreads();
    #pragma unroll
    for (int off = 1; off < 1024; off <<= 1) {
        int t = (tid >= off) ? sums[tid - off] : 0;
        __syncthreads();
        sums[tid] += t;
        __syncthreads();
    }
    int run = (tid > 0) ? sums[tid - 1] : 0;
    for (int i = b; i < e; i++) {
        row_ptr[i] = run;
        nextp[i] = run;
        run += counts[i];
    }
    if (tid == 0) row_ptr[N] = sums[1023];
}

__global__ __launch_bounds__(256) void fill_csr_kernel(const int* __restrict__ src,
                                                       const int* __restrict__ dst,
                                                       const float* __restrict__ ew,
                                                       int* __restrict__ next,
                                                       int2* __restrict__ csr_sw, int E) {
    int i = blockIdx.x * blockDim.x + threadIdx.x;
    if (i < E) {
        int d = dst[i];
        int pos = atomicAdd(&next[d], 1);
        csr_sw[pos] = make_int2(src[i], __float_as_int(ew[i]));
    }
}

// ---------------- X -> fp16 one-shot conversion ----------------

__global__ __launch_bounds__(256) void convert_x_kernel(const float* __restrict__ x,
                                                        unsigned short* __restrict__ X16,
                                                        int total8) {
    int stride = gridDim.x * 256;
    for (int i = blockIdx.x * 256 + threadIdx.x; i < total8; i += stride) {
        const float* p = x + (size_t)i * 8;
        float4 a = *(const float4*)p;
        float4 b = *(const float4*)(p + 4);
        half8 h;
        h[0] = (_Float16)a.x; h[1] = (_Float16)a.y;
        h[2] = (_Float16)a.z; h[3] = (_Float16)a.w;
        h[4] = (_Float16)b.x; h[5] = (_Float16)b.y;
        h[6] = (_Float16)b.z; h[7] = (_Float16)b.w;
        *(half8*)(X16 + (size_t)i * 8) = h;
    }
}

// ---------------- fused weight split: w [K][N] fp32 -> [NPAD][KPAD] fp16 hi/lo ----------------

__global__ __launch_bounds__(256) void split_weights_kernel(
        const float* __restrict__ w1, const float* __restrict__ w2, const float* __restrict__ w3,
        unsigned short* __restrict__ W1H, unsigned short* __restrict__ W1L,
        unsigned short* __restrict__ W2H, unsigned short* __restrict__ W2L,
        unsigned short* __restrict__ W3H, unsigned short* __restrict__ W3L) {
    int i = blockIdx.x * 256 + threadIdx.x;
    const float* w; unsigned short *H, *L; int K, N, KP;
    if (i < 163840) {                       // 320*512
        w = w1; H = W1H; L = W1L; K = 512; N = 300; KP = 512;
    } else if (i < 163840 + 81920) {        // 256*320
        i -= 163840; w = w2; H = W2H; L = W2L; K = 300; N = 200; KP = 320;
    } else {                                // 64*256
        i -= 245760; w = w3; H = W3H; L = W3L; K = 200; N = 40; KP = 256;
    }
    int n = i / KP, k = i - n * KP;
    float a = (n < N && k < K) ? w[(size_t)k * N + n] : 0.f;
    unsigned short h = f2h(a);
    H[i] = h;
    L[i] = f2h(a - h2f(h));
}

// ---------------- fp16 MFMA GEMM: B-only LDS, A direct global->VGPR ----------------

template <int KPAD, int NT, bool AF32>
__global__ __launch_bounds__(256, 3) void gemm_f16_kernel(
        const void* __restrict__ A_,
        const unsigned short* __restrict__ Bhi, const unsigned short* __restrict__ Blo,
        unsigned short* __restrict__ C, int M, int NP, int MT) {
    __shared__ short Bs_hi[4096];
    __shared__ short Bs_lo[4096];

    const int id = blockIdx.x;
    const int g  = id / (8 * NT);
    const int r  = id % (8 * NT);
    const int nt = r >> 3;
    const int x  = r & 7;
    const int mt = g * 8 + x;
    if (mt >= MT) return;

    const int tid = threadIdx.x;
    const int wave = tid >> 6, lane = tid & 63;
    const int lm = lane & 15, quad = lane >> 4;
    const int bm = mt * 256, bn = nt * 64;

    f32x4 acc[4][4] = {};

    for (int k0 = 0; k0 < KPAD; k0 += 64) {
        #pragma unroll
        for (int i = 0; i < 2; i++) {
            int t = i * 256 + tid;
            int n = t >> 3;
            int c = (t & 7) ^ (n & 7);
            size_t goff = (size_t)(bn + n) * KPAD + (size_t)(k0 + c * 8);
            int lbase = (i * 256 + wave * 64) * 8;
            stage16(Bhi + goff, Bs_hi + lbase);
            stage16(Blo + goff, Bs_lo + lbase);
        }
        __syncthreads();

        #pragma unroll
        for (int h = 0; h < 2; h++) {
            const int cidx = h * 4 + quad;
            half8 a[4], bh[4], bl[4];
            #pragma unroll
            for (int i = 0; i < 4; i++) {
                int row = bm + wave * 64 + i * 16 + lm;
                row = row < M ? row : M - 1;
                size_t off = (size_t)row * KPAD + (size_t)(k0 + cidx * 8);
                if (AF32) {
                    const float* ap = (const float*)A_ + off;
                    float4 p = *(const float4*)ap;
                    float4 q = *(const float4*)(ap + 4);
                    half8 t8;
                    t8[0] = (_Float16)p.x; t8[1] = (_Float16)p.y;
                    t8[2] = (_Float16)p.z; t8[3] = (_Float16)p.w;
                    t8[4] = (_Float16)q.x; t8[5] = (_Float16)q.y;
                    t8[6] = (_Float16)q.z; t8[7] = (_Float16)q.w;
                    a[i] = t8;
                } else {
                    a[i] = *(const half8*)((const unsigned short*)A_ + off);
                }
            }
            #pragma unroll
            for (int j = 0; j < 4; j++) {
                int n = j * 16 + lm;
                int off = (n * 8 + (cidx ^ (n & 7))) * 8;
                bh[j] = *(const half8*)(Bs_hi + off);
                bl[j] = *(const half8*)(Bs_lo + off);
            }
            #pragma unroll
            for (int i = 0; i < 4; i++)
                #pragma unroll
                for (int j = 0; j < 4; j++) {
                    acc[i][j] = __builtin_amdgcn_mfma_f32_16x16x32_f16(a[i], bh[j], acc[i][j], 0, 0, 0);
                    acc[i][j] = __builtin_amdgcn_mfma_f32_16x16x32_f16(a[i], bl[j], acc[i][j], 0, 0, 0);
                }
        }
        __syncthreads();
    }

    #pragma unroll
    for (int i = 0; i < 4; i++) {
        #pragma unroll
        for (int j = 0; j < 4; j++) {
            #pragma unroll
            for (int r2 = 0; r2 < 4; r2++) {
                int row = bm + wave * 64 + i * 16 + quad * 4 + r2;
                int col = bn + j * 16 + lm;
                if (row < M)
                    C[(size_t)row * NP + col] = f2h(acc[i][j][r2]);
            }
        }
    }
}

// ---------------- SpMM (CSR by dst), persistent blocks, one wave per dst row ----------------
// Depth-4 double-buffered gather pipeline:
//   - src indices broadcast via readlane -> SGPR addressing (zero VGPR for addresses)
//   - batch b+1 csr read + gathers issued BEFORE batch b is consumed (4-8 loads in flight)
//   - WIDE (layer1 NP=320): one dwordx4/edge, lanes 0..39; narrow (NP=256): dwordx2, 64 lanes
// No launch_bounds occupancy forcing (round-2 spill lesson).

template <bool W> struct GVsel { typedef uint2 T; };
template <> struct GVsel<true> { typedef uint4 T; };

__device__ __forceinline__ void fmaN(float* acc, uint4 g, float w) {
    float2 a;
    a = h2f2(g.x); acc[0] += w * a.x; acc[1] += w * a.y;
    a = h2f2(g.y); acc[2] += w * a.x; acc[3] += w * a.y;
    a = h2f2(g.z); acc[4] += w * a.x; acc[5] += w * a.y;
    a = h2f2(g.w); acc[6] += w * a.x; acc[7] += w * a.y;
}
__device__ __forceinline__ void fmaN(float* acc, uint2 g, float w) {
    float2 a;
    a = h2f2(g.x); acc[0] += w * a.x; acc[1] += w * a.y;
    a = h2f2(g.y); acc[2] += w * a.x; acc[3] += w * a.y;
}

template <int F, int NP>
__global__ __launch_bounds__(256) void spmm_relu_f16_kernel(
        const int* __restrict__ row_ptr, const int2* __restrict__ csr_sw,
        const unsigned short* __restrict__ support, const float* __restrict__ bias,
        unsigned short* __restrict__ outp, int N) {
    constexpr bool WIDE = (NP > 256);
    constexpr int LPE = WIDE ? NP / 8 : NP / 4;   // 40 / 64 lanes per edge
    constexpr int AK  = WIDE ? 8 : 4;             // feats per lane
    typedef typename GVsel<WIDE>::T GV;

    const int lane = threadIdx.x & 63;
    const int nwaves = gridDim.x * 4;
    const int lc = WIDE ? min(lane, LPE - 1) : lane;

    for (int row = blockIdx.x * 4 + (threadIdx.x >> 6); row < N; row += nwaves) {
        const int beg = row_ptr[row], end = row_ptr[row + 1];
        const int deg = end - beg;
        float acc[AK];
        #pragma unroll
        for (int k = 0; k < AK; k++) acc[k] = 0.f;

        auto csr_load = [&](int b) -> int2 {
            int idx = min(beg + (b << 2) + min(lane, 3), end - 1);
            return csr_sw[idx];
        };
        auto bcast = [&](int2 cs, int b, int* s, float* w) {
            int base = beg + (b << 2);
            #pragma unroll
            for (int q = 0; q < 4; q++) {
                s[q] = __builtin_amdgcn_readlane(cs.x, q);
                float wv = __uint_as_float((unsigned)__builtin_amdgcn_readlane(cs.y, q));
                w[q] = (base + q < end) ? wv : 0.f;
            }
        };
        auto issue = [&](GV* A, const int* s) {
            #pragma unroll
            for (int q = 0; q < 4; q++) {
                const unsigned short* sp = support + (size_t)s[q] * NP;
                A[q] = *(const GV*)(sp + lc * AK);
            }
        };
        auto consume = [&](const GV* A, const float* w) {
            #pragma unroll
            for (int q = 0; q < 4; q++) fmaN(acc, A[q], w[q]);
        };

        if (deg > 0) {
            const int nb = (deg + 3) >> 2;
            int sa[4]; float wa[4];
            int sb[4]; float wb[4];
            GV A[4], B[4];

            int2 cs = csr_load(0);
            bcast(cs, 0, sa, wa);
            issue(A, sa);
            int b = 0;
            while (b + 1 < nb) {
                int2 cs2 = csr_load(b + 1);
                bcast(cs2, b + 1, sb, wb);
                issue(B, sb);
                consume(A, wa);          // B gathers in flight during these FMAs
                b++;
                if (b + 1 < nb) {
                    cs = csr_load(b + 1);
                    bcast(cs, b + 1, sa, wa);
                    issue(A, sa);
                    consume(B, wb);      // A gathers in flight
                    b++;
                } else {
                    consume(B, wb);
                    b++;
                }
            }
            if (b < nb) consume(A, wa);  // nb odd tail (incl. nb==1)
        }

        if constexpr (WIDE) {
            if (lane < LPE) {
                half8 o;
                #pragma unroll
                for (int k = 0; k < 8; k++) {
                    int f = lane * 8 + k;
                    float v = (f < F) ? fmaxf(acc[k] + bias[f], 0.f) : 0.f;
                    o[k] = (_Float16)v;
                }
                *(half8*)(outp + (size_t)row * NP + lane * 8) = o;
            }
        } else {
            bool real = lane < F / 4;
            float4 bb = real ? ((const float4*)bias)[lane] : make_float4(0, 0, 0, 0);
            float v0 = real ? fmaxf(acc[0] + bb.x, 0.f) : 0.f;
            float v1 = real ? fmaxf(acc[1] + bb.y, 0.f) : 0.f;
            float v2 = real ? fmaxf(acc[2] + bb.z, 0.f) : 0.f;
            float v3 = real ? fmaxf(acc[3] + bb.w, 0.f) : 0.f;
            u32x2 w;
            w.x = pack2h(v0, v1);
            w.y = pack2h(v2, v3);
            *(u32x2*)(outp + (size_t)row * NP + lane * 4) = w;
        }
    }
}

// layer 3: aggregation (F=40, stride 64 fp16) + bias + softmax fused, persistent blocks.

__global__ __launch_bounds__(256) void spmm_softmax_kernel(
        const int* __restrict__ row_ptr, const int2* __restrict__ csr_sw,
        const unsigned short* __restrict__ support, const float* __restrict__ bias,
        float* __restrict__ out, int N) {
    const int lane = threadIdx.x & 63;
    const int nwaves = gridDim.x * 4;

    const int g = lane / 20;           // 0,1,2 active; 3 = idle lanes 60-63
    const int t = lane - g * 20;       // 0..19 (class dword index)
    const bool lact = lane < 60;

    for (int row = blockIdx.x * 4 + (threadIdx.x >> 6); row < N; row += nwaves) {
        int beg = row_ptr[row], end = row_ptr[row + 1];

        float a0 = 0.f, a1 = 0.f;
        for (int e = beg; e < end; e += 3) {
            int ei = e + g;
            bool v = lact && (ei < end);
            int2 sw = csr_sw[v ? ei : beg];
            float w = v ? __int_as_float(sw.y) : 0.f;
            unsigned u = *(const unsigned*)(support + (size_t)sw.x * 64 + t * 2);
            float2 aa = h2f2(u);
            a0 += w * aa.x;
            a1 += w * aa.y;
        }
        a0 += __shfl(a0, lane + 20) + __shfl(a0, lane + 40);
        a1 += __shfl(a1, lane + 20) + __shfl(a1, lane + 40);

        const bool act = lane < 20;
        float v0 = 0.f, v1 = 0.f, m = -INFINITY;
        if (act) {
            float2 bb = ((const float2*)bias)[t];
            v0 = a0 + bb.x;
            v1 = a1 + bb.y;
            m = fmaxf(v0, v1);
        }
        #pragma unroll
        for (int off = 16; off; off >>= 1) m = fmaxf(m, __shfl_xor(m, off));
        float e0 = 0.f, e1 = 0.f;
        if (act) { e0 = expf(v0 - m); e1 = expf(v1 - m); }
        float s = e0 + e1;
        #pragma unroll
        for (int off = 16; off; off >>= 1) s += __shfl_xor(s, off);
        if (act) {
            float inv = 1.f / s;
            *(float2*)(out + (size_t)row * NCLASS + t * 2) = make_float2(e0 * inv, e1 * inv);
        }
    }
}

// ---------------- launch ----------------

extern "C" void kernel_launch(void* const* d_in, const int* in_sizes, int n_in,
                              void* d_out, int out_size, void* d_ws, size_t ws_size,
                              hipStream_t stream) {
    const float* x   = (const float*)d_in[0];
    const int*   ei  = (const int*)d_in[1];
    const float* ew  = (const float*)d_in[2];
    const float* w1  = (const float*)d_in[3];
    const float* b1  = (const float*)d_in[4];
    const float* w2  = (const float*)d_in[5];
    const float* b2  = (const float*)d_in[6];
    const float* w3  = (const float*)d_in[7];
    const float* b3  = (const float*)d_in[8];
    float* out = (float*)d_out;

    const int N = in_sizes[0] / NFEAT;   // 100000
    const int E = in_sizes[2];           // 3200000
    const int* src = ei;
    const int* dst = ei + E;

    const int KP1 = 512, NP1 = 320, NT1 = 5;   // layer1: K=512, N=300
    const int KP2 = 320, NP2 = 256, NT2 = 4;   // layer2: K=300, N=200
    const int KP3 = 256, NP3 = 64,  NT3 = 1;   // layer3: K=200, N=40

    char* base = (char*)d_ws;
    unsigned short* X16 = (unsigned short*)(base);   // 100000*512*2, dead after gemm1
    unsigned short* H1H = (unsigned short*)(base);   // 100000*320*2 overlay
    unsigned short* H2H = (unsigned short*)(base);   // 100000*256*2 overlay

    unsigned short* support = (unsigned short*)(base + 102400256);

    size_t wo = 102400256 + 64000256;
    auto walloc = [&](size_t bytes) { void* r = base + wo; wo += (bytes + 255) & ~(size_t)255; return r; };
    unsigned short* W1H = (unsigned short*)walloc((size_t)NP1 * KP1 * 2);
    unsigned short* W1L = (unsigned short*)walloc((size_t)NP1 * KP1 * 2);
    unsigned short* W2H = (unsigned short*)walloc((size_t)NP2 * KP2 * 2);
    unsigned short* W2L = (unsigned short*)walloc((size_t)NP2 * KP2 * 2);
    unsigned short* W3H = (unsigned short*)walloc((size_t)NP3 * KP3 * 2);
    unsigned short* W3L = (unsigned short*)walloc((size_t)NP3 * KP3 * 2);
    int*  counts  = (int*)walloc((size_t)N * 4);
    int*  row_ptr = (int*)walloc((size_t)(N + 1) * 4);
    int*  nextp   = (int*)walloc((size_t)N * 4);
    int2* csr_sw  = (int2*)walloc((size_t)E * 8);

    const int MT = (N + 255) / 256;              // 391 M-tiles
    const int G  = (MT + 7) / 8;
    const int SPMM_BLOCKS = 2048;                // persistent, 8 blocks/CU

    // ---- CSR build ----
    hipMemsetAsync(counts, 0, (size_t)N * 4, stream);
    count_dst_kernel<<<(E + 255) / 256, 256, 0, stream>>>(dst, counts, E);
    scan_kernel<<<1, 1024, 0, stream>>>(counts, row_ptr, nextp, N);
    fill_csr_kernel<<<(E + 255) / 256, 256, 0, stream>>>(src, dst, ew, nextp, csr_sw, E);

    // ---- weight conversion + X conversion ----
    split_weights_kernel<<<1024, 256, 0, stream>>>(w1, w2, w3, W1H, W1L, W2H, W2L, W3H, W3L);
    convert_x_kernel<<<2048, 256, 0, stream>>>(x, X16, N * NFEAT / 8);

    // ---- layer 1 ----
    gemm_f16_kernel<KP1, NT1, false><<<G * 8 * NT1, 256, 0, stream>>>(
        X16, W1H, W1L, support, N, NP1, MT);
    spmm_relu_f16_kernel<H1, NP1><<<SPMM_BLOCKS, 256, 0, stream>>>(row_ptr, csr_sw, support, b1, H1H, N);

    // ---- layer 2 ----
    gemm_f16_kernel<KP2, NT2, false><<<G * 8 * NT2, 256, 0, stream>>>(
        H1H, W2H, W2L, support, N, NP2, MT);
    spmm_relu_f16_kernel<H2, NP2><<<SPMM_BLOCKS, 256, 0, stream>>>(row_ptr, csr_sw, support, b2, H2H, N);

    // ---- layer 3 ----
    gemm_f16_kernel<KP3, NT3, false><<<G * 8 * NT3, 256, 0, stream>>>(
        H2H, W3H, W3L, support, N, NP3, MT);
    spmm_softmax_kernel<<<SPMM_BLOCKS, 256, 0, stream>>>(row_ptr, csr_sw, support, b3, out, N);
}

// Round 5
// 1708.418 us; speedup vs baseline: 1.1289x; 1.0096x over previous
//
#include <hip/hip_runtime.h>
#include <hip/hip_bf16.h>
#include <hip/hip_fp16.h>
#include <math.h>

#define NFEAT 512
#define H1 300
#define H2 200
#define NCLASS 40

typedef __attribute__((ext_vector_type(8))) _Float16 half8;
typedef __attribute__((ext_vector_type(4))) float f32x4;
typedef __attribute__((ext_vector_type(2))) unsigned int u32x2;

__device__ __forceinline__ void stage16(const void* gptr, void* ldsptr) {
    __builtin_amdgcn_global_load_lds(
        (const __attribute__((address_space(1))) unsigned int*)gptr,
        (__attribute__((address_space(3))) unsigned int*)ldsptr,
        16, 0, 0);
}

__device__ __forceinline__ unsigned short f2h(float f) {
    return __half_as_ushort(__float2half(f));
}
__device__ __forceinline__ float h2f(unsigned short u) {
    return __half2float(__ushort_as_half(u));
}
__device__ __forceinline__ float2 h2f2(unsigned int u) {
    __half2 h = *reinterpret_cast<__half2*>(&u);
    return __half22float2(h);
}
__device__ __forceinline__ unsigned pack2h(float a, float b) {
    return (unsigned)f2h(a) | ((unsigned)f2h(b) << 16);
}

// ---------------- CSR construction ----------------

__global__ __launch_bounds__(256) void count_dst_kernel(const int* __restrict__ dst,
                                                        int* __restrict__ counts, int E) {
    int i = blockIdx.x * blockDim.x + threadIdx.x;
    if (i < E) atomicAdd(&counts[dst[i]], 1);
}

__global__ __launch_bounds__(1024) void scan_kernel(const int* __restrict__ counts,
                                                    int* __restrict__ row_ptr,
                                                    int* __restrict__ nextp, int N) {
    __shared__ int sums[1024];
    const int tid = threadIdx.x;
    const int CH = (N + 1023) >> 10;
    const int b = tid * CH;
    const int e = min(b + CH, N);
    int s = 0;
    for (int i = b; i < e; i++) s += counts[i];
    sums[tid] = s;
    __syncthreads();
    #pragma unroll
    for (int off = 1; off < 1024; off <<= 1) {
        int t = (tid >= off) ? sums[tid - off] : 0;
        __syncthreads();
        sums[tid] += t;
        __syncthreads();
    }
    int run = (tid > 0) ? sums[tid - 1] : 0;
    for (int i = b; i < e; i++) {
        row_ptr[i] = run;
        nextp[i] = run;
        run += counts[i];
    }
    if (tid == 0) row_ptr[N] = sums[1023];
}

__global__ __launch_bounds__(256) void fill_csr_kernel(const int* __restrict__ src,
                                                       const int* __restrict__ dst,
                                                       const float* __restrict__ ew,
                                                       int* __restrict__ next,
                                                       int2* __restrict__ csr_sw, int E) {
    int i = blockIdx.x * blockDim.x + threadIdx.x;
    if (i < E) {
        int d = dst[i];
        int pos = atomicAdd(&next[d], 1);
        csr_sw[pos] = make_int2(src[i], __float_as_int(ew[i]));
    }
}

// ---------------- X -> fp16 one-shot conversion ----------------

__global__ __launch_bounds__(256) void convert_x_kernel(const float* __restrict__ x,
                                                        unsigned short* __restrict__ X16,
                                                        int total8) {
    int stride = gridDim.x * 256;
    for (int i = blockIdx.x * 256 + threadIdx.x; i < total8; i += stride) {
        const float* p = x + (size_t)i * 8;
        float4 a = *(const float4*)p;
        float4 b = *(const float4*)(p + 4);
        half8 h;
        h[0] = (_Float16)a.x; h[1] = (_Float16)a.y;
        h[2] = (_Float16)a.z; h[3] = (_Float16)a.w;
        h[4] = (_Float16)b.x; h[5] = (_Float16)b.y;
        h[6] = (_Float16)b.z; h[7] = (_Float16)b.w;
        *(half8*)(X16 + (size_t)i * 8) = h;
    }
}

// ---------------- fused weight split: w [K][N] fp32 -> [NPAD][KPAD] fp16 hi/lo ----------------

__global__ __launch_bounds__(256) void split_weights_kernel(
        const float* __restrict__ w1, const float* __restrict__ w2, const float* __restrict__ w3,
        unsigned short* __restrict__ W1H, unsigned short* __restrict__ W1L,
        unsigned short* __restrict__ W2H, unsigned short* __restrict__ W2L,
        unsigned short* __restrict__ W3H, unsigned short* __restrict__ W3L) {
    int i = blockIdx.x * 256 + threadIdx.x;
    const float* w; unsigned short *H, *L; int K, N, KP;
    if (i < 163840) {                       // 320*512
        w = w1; H = W1H; L = W1L; K = 512; N = 300; KP = 512;
    } else if (i < 163840 + 81920) {        // 256*320
        i -= 163840; w = w2; H = W2H; L = W2L; K = 300; N = 200; KP = 320;
    } else {                                // 64*256
        i -= 245760; w = w3; H = W3H; L = W3L; K = 200; N = 40; KP = 256;
    }
    int n = i / KP, k = i - n * KP;
    float a = (n < N && k < K) ? w[(size_t)k * N + n] : 0.f;
    unsigned short h = f2h(a);
    H[i] = h;
    L[i] = f2h(a - h2f(h));
}

// ---------------- fp16 MFMA GEMM: B-only LDS, A direct global->VGPR ----------------

template <int KPAD, int NT, bool AF32>
__global__ __launch_bounds__(256, 3) void gemm_f16_kernel(
        const void* __restrict__ A_,
        const unsigned short* __restrict__ Bhi, const unsigned short* __restrict__ Blo,
        unsigned short* __restrict__ C, int M, int NP, int MT) {
    __shared__ short Bs_hi[4096];
    __shared__ short Bs_lo[4096];

    const int id = blockIdx.x;
    const int g  = id / (8 * NT);
    const int r  = id % (8 * NT);
    const int nt = r >> 3;
    const int x  = r & 7;
    const int mt = g * 8 + x;
    if (mt >= MT) return;

    const int tid = threadIdx.x;
    const int wave = tid >> 6, lane = tid & 63;
    const int lm = lane & 15, quad = lane >> 4;
    const int bm = mt * 256, bn = nt * 64;

    f32x4 acc[4][4] = {};

    for (int k0 = 0; k0 < KPAD; k0 += 64) {
        #pragma unroll
        for (int i = 0; i < 2; i++) {
            int t = i * 256 + tid;
            int n = t >> 3;
            int c = (t & 7) ^ (n & 7);
            size_t goff = (size_t)(bn + n) * KPAD + (size_t)(k0 + c * 8);
            int lbase = (i * 256 + wave * 64) * 8;
            stage16(Bhi + goff, Bs_hi + lbase);
            stage16(Blo + goff, Bs_lo + lbase);
        }
        __syncthreads();

        #pragma unroll
        for (int h = 0; h < 2; h++) {
            const int cidx = h * 4 + quad;
            half8 a[4], bh[4], bl[4];
            #pragma unroll
            for (int i = 0; i < 4; i++) {
                int row = bm + wave * 64 + i * 16 + lm;
                row = row < M ? row : M - 1;
                size_t off = (size_t)row * KPAD + (size_t)(k0 + cidx * 8);
                if (AF32) {
                    const float* ap = (const float*)A_ + off;
                    float4 p = *(const float4*)ap;
                    float4 q = *(const float4*)(ap + 4);
                    half8 t8;
                    t8[0] = (_Float16)p.x; t8[1] = (_Float16)p.y;
                    t8[2] = (_Float16)p.z; t8[3] = (_Float16)p.w;
                    t8[4] = (_Float16)q.x; t8[5] = (_Float16)q.y;
                    t8[6] = (_Float16)q.z; t8[7] = (_Float16)q.w;
                    a[i] = t8;
                } else {
                    a[i] = *(const half8*)((const unsigned short*)A_ + off);
                }
            }
            #pragma unroll
            for (int j = 0; j < 4; j++) {
                int n = j * 16 + lm;
                int off = (n * 8 + (cidx ^ (n & 7))) * 8;
                bh[j] = *(const half8*)(Bs_hi + off);
                bl[j] = *(const half8*)(Bs_lo + off);
            }
            #pragma unroll
            for (int i = 0; i < 4; i++)
                #pragma unroll
                for (int j = 0; j < 4; j++) {
                    acc[i][j] = __builtin_amdgcn_mfma_f32_16x16x32_f16(a[i], bh[j], acc[i][j], 0, 0, 0);
                    acc[i][j] = __builtin_amdgcn_mfma_f32_16x16x32_f16(a[i], bl[j], acc[i][j], 0, 0, 0);
                }
        }
        __syncthreads();
    }

    #pragma unroll
    for (int i = 0; i < 4; i++) {
        #pragma unroll
        for (int j = 0; j < 4; j++) {
            #pragma unroll
            for (int r2 = 0; r2 < 4; r2++) {
                int row = bm + wave * 64 + i * 16 + quad * 4 + r2;
                int col = bn + j * 16 + lm;
                if (row < M)
                    C[(size_t)row * NP + col] = f2h(acc[i][j][r2]);
            }
        }
    }
}

// ---------------- SpMM (CSR by dst), one wave per dst row ----------------
// Whole-row CSR preload: one lane-parallel 8B load covers up to 64 edges; src/w
// then come from readlane (compile-time lane idx) -> NO csr wait inside the
// gather pipeline. 3-deep statically-unrolled rolling pipeline: 12 gathers in
// flight while 4 edges of FMAs retire. Pad lanes get w=0 + clamped address.
// deg>64 (prob ~1e-9/row for Poisson(32)) falls back to a serial loop.

template <bool W> struct GVsel { typedef uint2 T; };
template <> struct GVsel<true> { typedef uint4 T; };

__device__ __forceinline__ void fmaN(float* acc, uint4 g, float w) {
    float2 a;
    a = h2f2(g.x); acc[0] += w * a.x; acc[1] += w * a.y;
    a = h2f2(g.y); acc[2] += w * a.x; acc[3] += w * a.y;
    a = h2f2(g.z); acc[4] += w * a.x; acc[5] += w * a.y;
    a = h2f2(g.w); acc[6] += w * a.x; acc[7] += w * a.y;
}
__device__ __forceinline__ void fmaN(float* acc, uint2 g, float w) {
    float2 a;
    a = h2f2(g.x); acc[0] += w * a.x; acc[1] += w * a.y;
    a = h2f2(g.y); acc[2] += w * a.x; acc[3] += w * a.y;
}

template <int F, int NP>
__global__ __launch_bounds__(256) void spmm_relu_f16_kernel(
        const int* __restrict__ row_ptr, const int2* __restrict__ csr_sw,
        const unsigned short* __restrict__ support, const float* __restrict__ bias,
        unsigned short* __restrict__ outp, int N) {
    constexpr bool WIDE = (NP > 256);
    constexpr int LPE = WIDE ? NP / 8 : NP / 4;   // 40 / 64 lanes per edge
    constexpr int AK  = WIDE ? 8 : 4;             // feats per lane
    typedef typename GVsel<WIDE>::T GV;

    const int lane = threadIdx.x & 63;
    const int row = blockIdx.x * 4 + (threadIdx.x >> 6);
    if (row >= N) return;
    const int lc = WIDE ? min(lane, LPE - 1) : lane;

    const int beg = row_ptr[row], end = row_ptr[row + 1];
    const int deg = end - beg;

    float acc[AK];
    #pragma unroll
    for (int k = 0; k < AK; k++) acc[k] = 0.f;

    if (deg > 0 && deg <= 64) {
        // ---- whole-row csr preload into lane registers ----
        const int2 cs = csr_sw[beg + min(lane, deg - 1)];
        const int sx = cs.x;
        const int wb = (lane < deg) ? cs.y : 0;   // pad lanes contribute 0

        const int nb = (deg + 3) >> 2;            // 1..16 batches of 4 edges

        GV b0[4], b1[4], b2[4];

        // issue batch bq into B (addresses SGPR via readlane; static bq)
        #define ISSUE(B, bq)                                                        \
            do {                                                                    \
                _Pragma("unroll")                                                   \
                for (int q = 0; q < 4; q++) {                                       \
                    int s = __builtin_amdgcn_readlane(sx, (bq) * 4 + q);            \
                    const unsigned short* sp = support + (size_t)s * NP;            \
                    B[q] = *(const GV*)(sp + lc * AK);                              \
                }                                                                   \
            } while (0)
        #define CONSUME(B, bq)                                                      \
            do {                                                                    \
                _Pragma("unroll")                                                   \
                for (int q = 0; q < 4; q++) {                                       \
                    float w = __uint_as_float(                                      \
                        (unsigned)__builtin_amdgcn_readlane(wb, (bq) * 4 + q));     \
                    fmaN(acc, B[q], w);                                             \
                }                                                                   \
            } while (0)

        ISSUE(b0, 0);
        if (nb > 1) ISSUE(b1, 1);
        if (nb > 2) ISSUE(b2, 2);
        #pragma unroll
        for (int b = 0; b < 16; b++) {
            if (b < nb) {
                if ((b % 3) == 0) {
                    CONSUME(b0, b);
                    if (b + 3 < nb) ISSUE(b0, b + 3);
                } else if ((b % 3) == 1) {
                    CONSUME(b1, b);
                    if (b + 3 < nb) ISSUE(b1, b + 3);
                } else {
                    CONSUME(b2, b);
                    if (b + 3 < nb) ISSUE(b2, b + 3);
                }
            }
        }
        #undef ISSUE
        #undef CONSUME
    } else if (deg > 64) {
        // rare fallback: serial, uniform csr load per edge
        for (int e = beg; e < end; e++) {
            int2 sw = csr_sw[e];
            float w = __int_as_float(sw.y);
            const unsigned short* sp = support + (size_t)sw.x * NP;
            GV g = *(const GV*)(sp + lc * AK);
            fmaN(acc, g, w);
        }
    }

    if constexpr (WIDE) {
        if (lane < LPE) {
            half8 o;
            #pragma unroll
            for (int k = 0; k < 8; k++) {
                int f = lane * 8 + k;
                float v = (f < F) ? fmaxf(acc[k] + bias[f], 0.f) : 0.f;
                o[k] = (_Float16)v;
            }
            *(half8*)(outp + (size_t)row * NP + lane * 8) = o;
        }
    } else {
        bool real = lane < F / 4;
        float4 bb = real ? ((const float4*)bias)[lane] : make_float4(0, 0, 0, 0);
        float v0 = real ? fmaxf(acc[0] + bb.x, 0.f) : 0.f;
        float v1 = real ? fmaxf(acc[1] + bb.y, 0.f) : 0.f;
        float v2 = real ? fmaxf(acc[2] + bb.z, 0.f) : 0.f;
        float v3 = real ? fmaxf(acc[3] + bb.w, 0.f) : 0.f;
        u32x2 w;
        w.x = pack2h(v0, v1);
        w.y = pack2h(v2, v3);
        *(u32x2*)(outp + (size_t)row * NP + lane * 4) = w;
    }
}

// layer 3: aggregation (F=40, stride 64 fp16) + bias + softmax fused.

__global__ __launch_bounds__(256) void spmm_softmax_kernel(
        const int* __restrict__ row_ptr, const int2* __restrict__ csr_sw,
        const unsigned short* __restrict__ support, const float* __restrict__ bias,
        float* __restrict__ out, int N) {
    int row = blockIdx.x * 4 + (threadIdx.x >> 6);
    int lane = threadIdx.x & 63;
    if (row >= N) return;
    int beg = row_ptr[row], end = row_ptr[row + 1];

    const int g = lane / 20;           // 0,1,2 active; 3 = idle lanes 60-63
    const int t = lane - g * 20;       // 0..19 (class dword index)
    const bool lact = lane < 60;

    float a0 = 0.f, a1 = 0.f;
    for (int e = beg; e < end; e += 3) {
        int ei = e + g;
        bool v = lact && (ei < end);
        int2 sw = csr_sw[v ? ei : beg];
        float w = v ? __int_as_float(sw.y) : 0.f;
        unsigned u = *(const unsigned*)(support + (size_t)sw.x * 64 + t * 2);
        float2 aa = h2f2(u);
        a0 += w * aa.x;
        a1 += w * aa.y;
    }
    a0 += __shfl(a0, lane + 20) + __shfl(a0, lane + 40);
    a1 += __shfl(a1, lane + 20) + __shfl(a1, lane + 40);

    const bool act = lane < 20;
    float v0 = 0.f, v1 = 0.f, m = -INFINITY;
    if (act) {
        float2 bb = ((const float2*)bias)[t];
        v0 = a0 + bb.x;
        v1 = a1 + bb.y;
        m = fmaxf(v0, v1);
    }
    #pragma unroll
    for (int off = 16; off; off >>= 1) m = fmaxf(m, __shfl_xor(m, off));
    float e0 = 0.f, e1 = 0.f;
    if (act) { e0 = expf(v0 - m); e1 = expf(v1 - m); }
    float s = e0 + e1;
    #pragma unroll
    for (int off = 16; off; off >>= 1) s += __shfl_xor(s, off);
    if (act) {
        float inv = 1.f / s;
        *(float2*)(out + (size_t)row * NCLASS + t * 2) = make_float2(e0 * inv, e1 * inv);
    }
}

// ---------------- launch ----------------

extern "C" void kernel_launch(void* const* d_in, const int* in_sizes, int n_in,
                              void* d_out, int out_size, void* d_ws, size_t ws_size,
                              hipStream_t stream) {
    const float* x   = (const float*)d_in[0];
    const int*   ei  = (const int*)d_in[1];
    const float* ew  = (const float*)d_in[2];
    const float* w1  = (const float*)d_in[3];
    const float* b1  = (const float*)d_in[4];
    const float* w2  = (const float*)d_in[5];
    const float* b2  = (const float*)d_in[6];
    const float* w3  = (const float*)d_in[7];
    const float* b3  = (const float*)d_in[8];
    float* out = (float*)d_out;

    const int N = in_sizes[0] / NFEAT;   // 100000
    const int E = in_sizes[2];           // 3200000
    const int* src = ei;
    const int* dst = ei + E;

    const int KP1 = 512, NP1 = 320, NT1 = 5;   // layer1: K=512, N=300
    const int KP2 = 320, NP2 = 256, NT2 = 4;   // layer2: K=300, N=200
    const int KP3 = 256, NP3 = 64,  NT3 = 1;   // layer3: K=200, N=40

    char* base = (char*)d_ws;
    unsigned short* X16 = (unsigned short*)(base);   // 100000*512*2, dead after gemm1
    unsigned short* H1H = (unsigned short*)(base);   // 100000*320*2 overlay
    unsigned short* H2H = (unsigned short*)(base);   // 100000*256*2 overlay

    unsigned short* support = (unsigned short*)(base + 102400256);

    size_t wo = 102400256 + 64000256;
    auto walloc = [&](size_t bytes) { void* r = base + wo; wo += (bytes + 255) & ~(size_t)255; return r; };
    unsigned short* W1H = (unsigned short*)walloc((size_t)NP1 * KP1 * 2);
    unsigned short* W1L = (unsigned short*)walloc((size_t)NP1 * KP1 * 2);
    unsigned short* W2H = (unsigned short*)walloc((size_t)NP2 * KP2 * 2);
    unsigned short* W2L = (unsigned short*)walloc((size_t)NP2 * KP2 * 2);
    unsigned short* W3H = (unsigned short*)walloc((size_t)NP3 * KP3 * 2);
    unsigned short* W3L = (unsigned short*)walloc((size_t)NP3 * KP3 * 2);
    int*  counts  = (int*)walloc((size_t)N * 4);
    int*  row_ptr = (int*)walloc((size_t)(N + 1) * 4);
    int*  nextp   = (int*)walloc((size_t)N * 4);
    int2* csr_sw  = (int2*)walloc((size_t)E * 8);

    const int MT = (N + 255) / 256;              // 391 M-tiles
    const int G  = (MT + 7) / 8;
    const int wgs = (N + 3) / 4;                 // 25000 blocks, 1 row/wave

    // ---- CSR build ----
    hipMemsetAsync(counts, 0, (size_t)N * 4, stream);
    count_dst_kernel<<<(E + 255) / 256, 256, 0, stream>>>(dst, counts, E);
    scan_kernel<<<1, 1024, 0, stream>>>(counts, row_ptr, nextp, N);
    fill_csr_kernel<<<(E + 255) / 256, 256, 0, stream>>>(src, dst, ew, nextp, csr_sw, E);

    // ---- weight conversion + X conversion ----
    split_weights_kernel<<<1024, 256, 0, stream>>>(w1, w2, w3, W1H, W1L, W2H, W2L, W3H, W3L);
    convert_x_kernel<<<2048, 256, 0, stream>>>(x, X16, N * NFEAT / 8);

    // ---- layer 1 ----
    gemm_f16_kernel<KP1, NT1, false><<<G * 8 * NT1, 256, 0, stream>>>(
        X16, W1H, W1L, support, N, NP1, MT);
    spmm_relu_f16_kernel<H1, NP1><<<wgs, 256, 0, stream>>>(row_ptr, csr_sw, support, b1, H1H, N);

    // ---- layer 2 ----
    gemm_f16_kernel<KP2, NT2, false><<<G * 8 * NT2, 256, 0, stream>>>(
        H1H, W2H, W2L, support, N, NP2, MT);
    spmm_relu_f16_kernel<H2, NP2><<<wgs, 256, 0, stream>>>(row_ptr, csr_sw, support, b2, H2H, N);

    // ---- layer 3 ----
    gemm_f16_kernel<KP3, NT3, false><<<G * 8 * NT3, 256, 0, stream>>>(
        H2H, W3H, W3L, support, N, NP3, MT);
    spmm_softmax_kernel<<<wgs, 256, 0, stream>>>(row_ptr, csr_sw, support, b3, out, N);
}